// Round 1
// baseline (1247.297 us; speedup 1.0000x reference)
//
#include <hip/hip_runtime.h>
#include <hip/hip_bf16.h>

#define B_ 512
#define T_ 49
#define I_ 96
#define H_ 1024
#define G_ 3072  /* 3*H */

typedef __attribute__((ext_vector_type(4))) float f32x4;
typedef __attribute__((ext_vector_type(8))) short s16x8;

__device__ __forceinline__ unsigned short f2bf(float f) {
    unsigned int u = __float_as_uint(f);
    unsigned int r = (u + 0x7FFFu + ((u >> 16) & 1u)) >> 16;
    return (unsigned short)r;
}

__device__ __forceinline__ float sigmoidf_(float x) {
    return 1.0f / (1.0f + __expf(-x));
}
__device__ __forceinline__ float tanhf_(float x) {
    // tanh(x) = 1 - 2/(exp(2x)+1); saturates correctly at +/-inf
    return 1.0f - 2.0f / (__expf(2.0f * x) + 1.0f);
}

// ---------------- quantize fp32 -> bf16 (W_hh, W_ih, enc_in) ----------------
__global__ void quantize_kernel(const float* __restrict__ Whh,
                                const float* __restrict__ Wih,
                                const float* __restrict__ x,
                                unsigned short* __restrict__ Whh_bf,
                                unsigned short* __restrict__ Wih_bf,
                                unsigned short* __restrict__ x_bf) {
    const long stride = (long)gridDim.x * blockDim.x;
    const long idx = (long)blockIdx.x * blockDim.x + threadIdx.x;

    const long nWhh4 = (long)G_ * H_ / 4;     // 786432
    const long nWih4 = (long)G_ * I_ / 4;     // 73728
    const long nX4   = (long)B_ * T_ * I_ / 4; // 589824

    for (long i = idx; i < nWhh4; i += stride) {
        float4 v = ((const float4*)Whh)[i];
        ushort4 o; o.x = f2bf(v.x); o.y = f2bf(v.y); o.z = f2bf(v.z); o.w = f2bf(v.w);
        ((ushort4*)Whh_bf)[i] = o;
    }
    for (long i = idx; i < nWih4; i += stride) {
        float4 v = ((const float4*)Wih)[i];
        ushort4 o; o.x = f2bf(v.x); o.y = f2bf(v.y); o.z = f2bf(v.z); o.w = f2bf(v.w);
        ((ushort4*)Wih_bf)[i] = o;
    }
    for (long i = idx; i < nX4; i += stride) {
        float4 v = ((const float4*)x)[i];
        ushort4 o; o.x = f2bf(v.x); o.y = f2bf(v.y); o.z = f2bf(v.z); o.w = f2bf(v.w);
        ((ushort4*)x_bf)[i] = o;
    }
}

// ---------------- one GRU step: h_out = GRUCell(x_t, h_in) ----------------
// Block tile: 64 b-rows x 32 j-cols. 4 waves: wave w -> (wm = w>>1) 32-row
// half, (wn = w&1) 16-col half. Each wave: 2 M-frags x 1 N-frag x 3 gates.
// MFMA 16x16x32 bf16, direct-from-global short8 operand loads (no LDS).
__global__ __launch_bounds__(256)
void gru_step(const unsigned short* __restrict__ Whh_bf,
              const unsigned short* __restrict__ Wih_bf,
              const unsigned short* __restrict__ x_bf,
              const float* __restrict__ b_ih,
              const float* __restrict__ b_hh,
              const float* __restrict__ h_in,            // fp32 prev h
              const unsigned short* __restrict__ hbf_in, // bf16 prev h
              float* __restrict__ h_out,
              unsigned short* __restrict__ hbf_out,
              int t, int first)
{
    const int tid = threadIdx.x;
    const int w   = tid >> 6;
    const int l   = tid & 63;
    const int l15 = l & 15;
    const int l4  = l >> 4;
    const int wm  = w >> 1;
    const int wn  = w & 1;

    const int blkb = blockIdx.x & 7;    // 8 b-tiles (512/64)
    const int blkj = blockIdx.x >> 3;   // 32 j-tiles (1024/32)
    const int b0w  = blkb * 64 + wm * 32;
    const int j0   = blkj * 32 + wn * 16;

    f32x4 accR[2], accZ[2], accNi[2], accNh[2];
#pragma unroll
    for (int m = 0; m < 2; ++m) {
        accR[m] = (f32x4){0.f, 0.f, 0.f, 0.f};
        accZ[m] = (f32x4){0.f, 0.f, 0.f, 0.f};
        accNi[m] = (f32x4){0.f, 0.f, 0.f, 0.f};
        accNh[m] = (f32x4){0.f, 0.f, 0.f, 0.f};
    }

    // ---- recurrent GEMM: gh = h @ W_hh^T  (K = 1024, 32 k-steps) ----
    if (!first) {
        const s16x8* Ah0 = (const s16x8*)(hbf_in + (long)(b0w + l15) * H_ + 8 * l4);
        const s16x8* Ah1 = (const s16x8*)(hbf_in + (long)(b0w + 16 + l15) * H_ + 8 * l4);
        const s16x8* Wr  = (const s16x8*)(Whh_bf + (long)(j0 + l15) * H_ + 8 * l4);
        const s16x8* Wz  = (const s16x8*)(Whh_bf + (long)(H_ + j0 + l15) * H_ + 8 * l4);
        const s16x8* Wn  = (const s16x8*)(Whh_bf + (long)(2 * H_ + j0 + l15) * H_ + 8 * l4);
#pragma unroll 4
        for (int ks = 0; ks < 32; ++ks) {
            s16x8 a0 = Ah0[ks * 4];
            s16x8 a1 = Ah1[ks * 4];
            s16x8 br = Wr[ks * 4];
            s16x8 bz = Wz[ks * 4];
            s16x8 bn = Wn[ks * 4];
            accR[0]  = __builtin_amdgcn_mfma_f32_16x16x32_bf16(a0, br, accR[0], 0, 0, 0);
            accR[1]  = __builtin_amdgcn_mfma_f32_16x16x32_bf16(a1, br, accR[1], 0, 0, 0);
            accZ[0]  = __builtin_amdgcn_mfma_f32_16x16x32_bf16(a0, bz, accZ[0], 0, 0, 0);
            accZ[1]  = __builtin_amdgcn_mfma_f32_16x16x32_bf16(a1, bz, accZ[1], 0, 0, 0);
            accNh[0] = __builtin_amdgcn_mfma_f32_16x16x32_bf16(a0, bn, accNh[0], 0, 0, 0);
            accNh[1] = __builtin_amdgcn_mfma_f32_16x16x32_bf16(a1, bn, accNh[1], 0, 0, 0);
        }
    }

    // ---- input GEMM: gi = x_t @ W_ih^T  (K = 96, 3 k-steps) ----
    {
        const s16x8* Ax0 = (const s16x8*)(x_bf + ((long)(b0w + l15) * T_ + t) * I_ + 8 * l4);
        const s16x8* Ax1 = (const s16x8*)(x_bf + ((long)(b0w + 16 + l15) * T_ + t) * I_ + 8 * l4);
        const s16x8* Vr  = (const s16x8*)(Wih_bf + (long)(j0 + l15) * I_ + 8 * l4);
        const s16x8* Vz  = (const s16x8*)(Wih_bf + (long)(H_ + j0 + l15) * I_ + 8 * l4);
        const s16x8* Vn  = (const s16x8*)(Wih_bf + (long)(2 * H_ + j0 + l15) * I_ + 8 * l4);
#pragma unroll
        for (int ks = 0; ks < 3; ++ks) {
            s16x8 a0 = Ax0[ks * 4];
            s16x8 a1 = Ax1[ks * 4];
            s16x8 br = Vr[ks * 4];
            s16x8 bz = Vz[ks * 4];
            s16x8 bn = Vn[ks * 4];
            accR[0]  = __builtin_amdgcn_mfma_f32_16x16x32_bf16(a0, br, accR[0], 0, 0, 0);
            accR[1]  = __builtin_amdgcn_mfma_f32_16x16x32_bf16(a1, br, accR[1], 0, 0, 0);
            accZ[0]  = __builtin_amdgcn_mfma_f32_16x16x32_bf16(a0, bz, accZ[0], 0, 0, 0);
            accZ[1]  = __builtin_amdgcn_mfma_f32_16x16x32_bf16(a1, bz, accZ[1], 0, 0, 0);
            accNi[0] = __builtin_amdgcn_mfma_f32_16x16x32_bf16(a0, bn, accNi[0], 0, 0, 0);
            accNi[1] = __builtin_amdgcn_mfma_f32_16x16x32_bf16(a1, bn, accNi[1], 0, 0, 0);
        }
    }

    // ---- epilogue: gates + blend (fp32) ----
    const int jg = j0 + l15;
    const float bihR = b_ih[jg], bihZ = b_ih[H_ + jg], bihN = b_ih[2 * H_ + jg];
    const float bhhR = b_hh[jg], bhhZ = b_hh[H_ + jg], bhhN = b_hh[2 * H_ + jg];

#pragma unroll
    for (int m = 0; m < 2; ++m) {
#pragma unroll
        for (int r = 0; r < 4; ++r) {
            const int row = b0w + m * 16 + l4 * 4 + r;
            const long off = (long)row * H_ + jg;
            const float hp = first ? 0.0f : h_in[off];
            const float rg = sigmoidf_(accR[m][r] + bihR + bhhR);
            const float zg = sigmoidf_(accZ[m][r] + bihZ + bhhZ);
            const float ng = tanhf_(accNi[m][r] + bihN + rg * (accNh[m][r] + bhhN));
            const float hn = (1.0f - zg) * ng + zg * hp;
            h_out[off] = hn;
            hbf_out[off] = f2bf(hn);
        }
    }
}

extern "C" void kernel_launch(void* const* d_in, const int* in_sizes, int n_in,
                              void* d_out, int out_size, void* d_ws, size_t ws_size,
                              hipStream_t stream) {
    const float* enc_in = (const float*)d_in[0];
    const float* W_ih   = (const float*)d_in[1];
    const float* W_hh   = (const float*)d_in[2];
    const float* b_ih   = (const float*)d_in[3];
    const float* b_hh   = (const float*)d_in[4];
    float* out = (float*)d_out;

    char* ws = (char*)d_ws;
    unsigned short* Whh_bf = (unsigned short*)(ws);             // 6,291,456 B
    unsigned short* Wih_bf = (unsigned short*)(ws + 6291456);   //   589,824 B
    unsigned short* x_bf   = (unsigned short*)(ws + 6881280);   // 4,816,896 B
    float* hA              = (float*)(ws + 11698176);           // 2,097,152 B
    float* hB              = (float*)(ws + 13795328);           // 2,097,152 B
    unsigned short* hbfA   = (unsigned short*)(ws + 15892480);  // 1,048,576 B
    unsigned short* hbfB   = (unsigned short*)(ws + 16941056);  // 1,048,576 B
    // total 17,989,632 B of d_ws used

    quantize_kernel<<<dim3(1024), dim3(256), 0, stream>>>(W_hh, W_ih, enc_in,
                                                          Whh_bf, Wih_bf, x_bf);

    for (int t = 0; t < T_; ++t) {
        const int first = (t == 0) ? 1 : 0;
        float* hi; unsigned short* hbi; float* ho; unsigned short* hbo;
        if (t & 1) { hi = hA; hbi = hbfA; ho = hB; hbo = hbfB; }
        else       { hi = hB; hbi = hbfB; ho = hA; hbo = hbfA; }
        if (t == T_ - 1) ho = out;  // last step writes d_out directly
        gru_step<<<dim3(256), dim3(256), 0, stream>>>(Whh_bf, Wih_bf, x_bf,
                                                      b_ih, b_hh, hi, hbi, ho, hbo,
                                                      t, first);
    }
}

// Round 2
// 664.881 us; speedup vs baseline: 1.8760x; 1.8760x over previous
//
#include <hip/hip_runtime.h>
#include <hip/hip_bf16.h>

#define B_ 512
#define T_ 49
#define I_ 96
#define H_ 1024
#define G_ 3072  /* 3*H */

typedef __attribute__((ext_vector_type(4))) float f32x4;
typedef __attribute__((ext_vector_type(8))) short s16x8;

__device__ __forceinline__ unsigned short f2bf(float f) {
    unsigned int u = __float_as_uint(f);
    unsigned int r = (u + 0x7FFFu + ((u >> 16) & 1u)) >> 16;
    return (unsigned short)r;
}

__device__ __forceinline__ float sigmoidf_(float x) {
    return 1.0f / (1.0f + __expf(-x));
}
__device__ __forceinline__ float tanhf_(float x) {
    return 1.0f - 2.0f / (__expf(2.0f * x) + 1.0f);
}

// ---------------- quantize fp32 -> bf16 (W_hh, W_ih, enc_in) ----------------
__global__ void quantize_kernel(const float* __restrict__ Whh,
                                const float* __restrict__ Wih,
                                const float* __restrict__ x,
                                unsigned short* __restrict__ Whh_bf,
                                unsigned short* __restrict__ Wih_bf,
                                unsigned short* __restrict__ x_bf) {
    const long stride = (long)gridDim.x * blockDim.x;
    const long idx = (long)blockIdx.x * blockDim.x + threadIdx.x;

    const long nWhh4 = (long)G_ * H_ / 4;
    const long nWih4 = (long)G_ * I_ / 4;
    const long nX4   = (long)B_ * T_ * I_ / 4;

    for (long i = idx; i < nWhh4; i += stride) {
        float4 v = ((const float4*)Whh)[i];
        ushort4 o; o.x = f2bf(v.x); o.y = f2bf(v.y); o.z = f2bf(v.z); o.w = f2bf(v.w);
        ((ushort4*)Whh_bf)[i] = o;
    }
    for (long i = idx; i < nWih4; i += stride) {
        float4 v = ((const float4*)Wih)[i];
        ushort4 o; o.x = f2bf(v.x); o.y = f2bf(v.y); o.z = f2bf(v.z); o.w = f2bf(v.w);
        ((ushort4*)Wih_bf)[i] = o;
    }
    for (long i = idx; i < nX4; i += stride) {
        float4 v = ((const float4*)x)[i];
        ushort4 o; o.x = f2bf(v.x); o.y = f2bf(v.y); o.z = f2bf(v.z); o.w = f2bf(v.w);
        ((ushort4*)x_bf)[i] = o;
    }
}

// ---------------- one GRU step ----------------
// 256 blocks x 512 threads (8 waves, 2/SIMD). Block tile 64b x 32j x 3 gates.
// Wave grid 4m x 2n: wave = 16b x 16j. XCD-grouped j mapping (bid&7 = XCD).
// Recurrent GEMM K=1024: LDS double-buffered, kc=128 (8 chunks), reg-staged.
// LDS pitch 136 bf16 (=17*16B): bank rotation by 4/row -> conflict-free b128.
__global__ __launch_bounds__(512)
void gru_step(const unsigned short* __restrict__ Whh_bf,
              const unsigned short* __restrict__ Wih_bf,
              const unsigned short* __restrict__ x_bf,
              const float* __restrict__ b_ih,
              const float* __restrict__ b_hh,
              const float* __restrict__ h_in,            // fp32 prev h
              const unsigned short* __restrict__ hbf_in, // bf16 prev h
              float* __restrict__ h_out,
              unsigned short* __restrict__ hbf_out,
              int t, int first)
{
    const int tid = threadIdx.x;
    const int w   = tid >> 6;
    const int l   = tid & 63;
    const int l15 = l & 15;
    const int l4  = l >> 4;
    const int wm  = w >> 1;   // 0..3 : 16-row m-slice
    const int wn  = w & 1;    // 0..1 : 16-col n-slice

    const int bid  = blockIdx.x;
    const int xcd  = bid & 7;
    const int idx  = bid >> 3;
    const int blkb = idx & 7;              // 8 b-tiles of 64
    const int blkj = xcd * 4 + (idx >> 3); // 32 j-tiles of 32, XCD-grouped
    const int b0   = blkb * 64;
    const int j0   = blkj * 32;

    __shared__ unsigned short Ab[2][64][136];  // h tile   [row b][k]
    __shared__ unsigned short Bb[2][96][136];  // W tile   [3g*32j][k]

    f32x4 accR  = (f32x4){0.f, 0.f, 0.f, 0.f};
    f32x4 accZ  = (f32x4){0.f, 0.f, 0.f, 0.f};
    f32x4 accNh = (f32x4){0.f, 0.f, 0.f, 0.f};
    f32x4 accNi = (f32x4){0.f, 0.f, 0.f, 0.f};

    // ---- input GEMM: gi = x_t @ W_ih^T  (K=96, direct from global) ----
    {
        const s16x8* Ax = (const s16x8*)(x_bf + ((long)(b0 + wm * 16 + l15) * T_ + t) * I_ + 8 * l4);
        const s16x8* Vr = (const s16x8*)(Wih_bf + (long)(j0 + wn * 16 + l15) * I_ + 8 * l4);
        const s16x8* Vz = (const s16x8*)(Wih_bf + (long)(H_ + j0 + wn * 16 + l15) * I_ + 8 * l4);
        const s16x8* Vn = (const s16x8*)(Wih_bf + (long)(2 * H_ + j0 + wn * 16 + l15) * I_ + 8 * l4);
#pragma unroll
        for (int ks = 0; ks < 3; ++ks) {
            s16x8 a  = Ax[ks * 4];
            s16x8 br = Vr[ks * 4];
            s16x8 bz = Vz[ks * 4];
            s16x8 bn = Vn[ks * 4];
            accR  = __builtin_amdgcn_mfma_f32_16x16x32_bf16(a, br, accR, 0, 0, 0);
            accZ  = __builtin_amdgcn_mfma_f32_16x16x32_bf16(a, bz, accZ, 0, 0, 0);
            accNi = __builtin_amdgcn_mfma_f32_16x16x32_bf16(a, bn, accNi, 0, 0, 0);
        }
    }

    // ---- recurrent GEMM: gh = h @ W_hh^T  (K=1024, LDS double-buffered) ----
    if (!first) {
        const int rowA = tid >> 4;   // 0..31
        const int cc   = tid & 15;   // 16B chunk within kc=128

        s16x8 rA0, rA1, rB0, rB1, rB2;

#define LOAD_CHUNK(c) {                                                                     \
        const long k0 = (long)(c) * 128;                                                    \
        rA0 = *(const s16x8*)(hbf_in + (long)(b0 + rowA) * H_ + k0 + cc * 8);               \
        rA1 = *(const s16x8*)(hbf_in + (long)(b0 + rowA + 32) * H_ + k0 + cc * 8);          \
        rB0 = *(const s16x8*)(Whh_bf + (long)(((rowA)      >> 5) * H_ + j0 + ((rowA)      & 31)) * H_ + k0 + cc * 8); \
        rB1 = *(const s16x8*)(Whh_bf + (long)(((rowA + 32) >> 5) * H_ + j0 + ((rowA + 32) & 31)) * H_ + k0 + cc * 8); \
        rB2 = *(const s16x8*)(Whh_bf + (long)(((rowA + 64) >> 5) * H_ + j0 + ((rowA + 64) & 31)) * H_ + k0 + cc * 8); }

#define STORE_CHUNK(buf) {                                  \
        *(s16x8*)&Ab[buf][rowA][cc * 8]      = rA0;         \
        *(s16x8*)&Ab[buf][rowA + 32][cc * 8] = rA1;         \
        *(s16x8*)&Bb[buf][rowA][cc * 8]      = rB0;         \
        *(s16x8*)&Bb[buf][rowA + 32][cc * 8] = rB1;         \
        *(s16x8*)&Bb[buf][rowA + 64][cc * 8] = rB2; }

        LOAD_CHUNK(0);
        STORE_CHUNK(0);
        __syncthreads();

        int cur = 0;
        for (int c = 0; c < 8; ++c) {
            if (c < 7) LOAD_CHUNK(c + 1);
#pragma unroll
            for (int ks = 0; ks < 4; ++ks) {
                s16x8 a  = *(const s16x8*)&Ab[cur][wm * 16 + l15][ks * 32 + l4 * 8];
                s16x8 br = *(const s16x8*)&Bb[cur][wn * 16 + l15][ks * 32 + l4 * 8];
                s16x8 bz = *(const s16x8*)&Bb[cur][32 + wn * 16 + l15][ks * 32 + l4 * 8];
                s16x8 bn = *(const s16x8*)&Bb[cur][64 + wn * 16 + l15][ks * 32 + l4 * 8];
                accR  = __builtin_amdgcn_mfma_f32_16x16x32_bf16(a, br, accR, 0, 0, 0);
                accZ  = __builtin_amdgcn_mfma_f32_16x16x32_bf16(a, bz, accZ, 0, 0, 0);
                accNh = __builtin_amdgcn_mfma_f32_16x16x32_bf16(a, bn, accNh, 0, 0, 0);
            }
            if (c < 7) STORE_CHUNK(cur ^ 1);
            __syncthreads();
            cur ^= 1;
        }
#undef LOAD_CHUNK
#undef STORE_CHUNK
    }

    // ---- epilogue: gates + blend (fp32) ----
    const int jg = j0 + wn * 16 + l15;
    const float bihR = b_ih[jg], bihZ = b_ih[H_ + jg], bihN = b_ih[2 * H_ + jg];
    const float bhhR = b_hh[jg], bhhZ = b_hh[H_ + jg], bhhN = b_hh[2 * H_ + jg];

#pragma unroll
    for (int r = 0; r < 4; ++r) {
        const int row = b0 + wm * 16 + l4 * 4 + r;
        const long off = (long)row * H_ + jg;
        const float hp = first ? 0.0f : h_in[off];
        const float rg = sigmoidf_(accR[r] + bihR + bhhR);
        const float zg = sigmoidf_(accZ[r] + bihZ + bhhZ);
        const float ng = tanhf_(accNi[r] + bihN + rg * (accNh[r] + bhhN));
        const float hn = (1.0f - zg) * ng + zg * hp;
        h_out[off] = hn;
        hbf_out[off] = f2bf(hn);
    }
}

extern "C" void kernel_launch(void* const* d_in, const int* in_sizes, int n_in,
                              void* d_out, int out_size, void* d_ws, size_t ws_size,
                              hipStream_t stream) {
    const float* enc_in = (const float*)d_in[0];
    const float* W_ih   = (const float*)d_in[1];
    const float* W_hh   = (const float*)d_in[2];
    const float* b_ih   = (const float*)d_in[3];
    const float* b_hh   = (const float*)d_in[4];
    float* out = (float*)d_out;

    char* ws = (char*)d_ws;
    unsigned short* Whh_bf = (unsigned short*)(ws);             // 6,291,456 B
    unsigned short* Wih_bf = (unsigned short*)(ws + 6291456);   //   589,824 B
    unsigned short* x_bf   = (unsigned short*)(ws + 6881280);   // 4,816,896 B
    float* hA              = (float*)(ws + 11698176);           // 2,097,152 B
    float* hB              = (float*)(ws + 13795328);           // 2,097,152 B
    unsigned short* hbfA   = (unsigned short*)(ws + 15892480);  // 1,048,576 B
    unsigned short* hbfB   = (unsigned short*)(ws + 16941056);  // 1,048,576 B

    quantize_kernel<<<dim3(1024), dim3(256), 0, stream>>>(W_hh, W_ih, enc_in,
                                                          Whh_bf, Wih_bf, x_bf);

    for (int t = 0; t < T_; ++t) {
        const int first = (t == 0) ? 1 : 0;
        float* hi; unsigned short* hbi; float* ho; unsigned short* hbo;
        if (t & 1) { hi = hA; hbi = hbfA; ho = hB; hbo = hbfB; }
        else       { hi = hB; hbi = hbfB; ho = hA; hbo = hbfA; }
        if (t == T_ - 1) ho = out;  // last step writes d_out directly
        gru_step<<<dim3(256), dim3(512), 0, stream>>>(Whh_bf, Wih_bf, x_bf,
                                                      b_ih, b_hh, hi, hbi, ho, hbo,
                                                      t, first);
    }
}